// Round 1
// baseline (1251.307 us; speedup 1.0000x reference)
//
#include <hip/hip_runtime.h>
#include <hip/hip_bf16.h>

#define N_TOK 65536
#define C_DIM 1024

typedef __hip_bfloat16 bf16;
typedef short short8 __attribute__((ext_vector_type(8)));
typedef short short4v __attribute__((ext_vector_type(4)));
typedef float f32x4 __attribute__((ext_vector_type(4)));

__device__ __forceinline__ void gload_lds16(const void* g, void* l) {
  __builtin_amdgcn_global_load_lds(
      (const __attribute__((address_space(1))) void*)g,
      (__attribute__((address_space(3))) void*)l, 16, 0, 0);
}

// ---------------- fp32 -> bf16 convert (vectorized) ----------------
__global__ void cvt_kernel(const float* __restrict__ in, bf16* __restrict__ out, long n4) {
  long i = (long)blockIdx.x * blockDim.x + threadIdx.x;
  const long stride = (long)gridDim.x * blockDim.x;
  for (; i < n4; i += stride) {
    const float4 v = ((const float4*)in)[i];
    union { bf16 h[4]; uint2 u; } p;
    p.h[0] = __float2bfloat16(v.x);
    p.h[1] = __float2bfloat16(v.y);
    p.h[2] = __float2bfloat16(v.z);
    p.h[3] = __float2bfloat16(v.w);
    ((uint2*)out)[i] = p.u;
  }
}

// ---------------- bf16 GEMM, C[m][n] = sum_k A[m][k]*B[n][k] + bias[n] ----------------
// m97 structure: 128x128 tile, BK=32, 4 waves (2x2), 4x4 16x16x32 frags/wave,
// global_load_lds width-16 staging, double-buffered LDS, 1 barrier/K-step.
template<bool OUT_BF16>
__global__ __launch_bounds__(256, 2) void gemm_bt(
    const bf16* __restrict__ A, const bf16* __restrict__ B,
    const float* __restrict__ bias, void* __restrict__ Cv,
    int M, int N, int K, int ntiles) {
  __shared__ __attribute__((aligned(16))) bf16 As[2][128 * 32];
  __shared__ __attribute__((aligned(16))) bf16 Bs[2][128 * 32];
  const int t = threadIdx.x;
  const int bid = blockIdx.x;
  const int mt = bid / ntiles, ntl = bid % ntiles;
  const long m0 = (long)mt * 128, n0 = (long)ntl * 128;
  const bf16* Ab = A + m0 * K;
  const bf16* Bb = B + n0 * K;

  const int lane = t & 63, wid = t >> 6;
  const int wr = (wid >> 1) * 64, wc = (wid & 1) * 64;
  const int lr = lane & 15, lk = (lane >> 4) * 8;

  f32x4 acc[4][4];
#pragma unroll
  for (int i = 0; i < 4; i++)
#pragma unroll
    for (int j = 0; j < 4; j++) acc[i][j] = f32x4{0.f, 0.f, 0.f, 0.f};

  // staging: [m][k] row-major tiles (row stride 32 bf16 = 64B), linear LDS fill.
  // lin in [0,512): m = lin>>2, k-offset = (lin&3)*8 elems; 16B per load.
  auto stage = [&](int buf, int kt) {
    const long kbase = (long)kt * 32;
#pragma unroll
    for (int r = 0; r < 2; ++r) {
      const int lin = r * 256 + t;
      const int mrow = lin >> 2, ke = (lin & 3) * 8;
      gload_lds16(Ab + (long)mrow * K + kbase + ke, &As[buf][lin * 8]);
      gload_lds16(Bb + (long)mrow * K + kbase + ke, &Bs[buf][lin * 8]);
    }
  };

  stage(0, 0);
  const int KT = K / 32;
  int cur = 0;
  for (int kt = 0; kt < KT; ++kt) {
    __syncthreads();  // drains vmcnt -> buf[cur] staged; prior reads of buf[cur^1] done
    if (kt + 1 < KT) stage(cur ^ 1, kt + 1);
    short8 a[4], b[4];
#pragma unroll
    for (int i = 0; i < 4; i++)
      a[i] = *(const short8*)&As[cur][(wr + i * 16 + lr) * 32 + lk];
#pragma unroll
    for (int j = 0; j < 4; j++)
      b[j] = *(const short8*)&Bs[cur][(wc + j * 16 + lr) * 32 + lk];
#pragma unroll
    for (int i = 0; i < 4; i++)
#pragma unroll
      for (int j = 0; j < 4; j++)
        acc[i][j] = __builtin_amdgcn_mfma_f32_16x16x32_bf16(a[i], b[j], acc[i][j], 0, 0, 0);
    cur ^= 1;
  }

  // epilogue: C col = lane&15, row = (lane>>4)*4 + reg (m89-verified layout)
  float bv[4];
#pragma unroll
  for (int j = 0; j < 4; j++) bv[j] = bias[n0 + wc + j * 16 + lr];
#pragma unroll
  for (int i = 0; i < 4; i++) {
    const long rbase = m0 + wr + i * 16 + ((lane >> 4) << 2);
#pragma unroll
    for (int q = 0; q < 4; q++) {
      const long row = rbase + q;
#pragma unroll
      for (int j = 0; j < 4; j++) {
        const float v = acc[i][j][q] + bv[j];
        const long col = n0 + wc + j * 16 + lr;
        if constexpr (OUT_BF16)
          ((bf16*)Cv)[row * N + col] = __float2bfloat16(v);
        else
          ((float*)Cv)[row * N + col] = v;
      }
    }
  }
}

// ---------------- per-token 16x16 attention, 1 wave/token ----------------
// scoresT = K @ Q^T via mfma_16x16x32 (lane: h=lane&15, g=(lane>>4)*4+reg)
// -> softmax over g (in-lane 4 + shfl_xor 16/32) -> attnT regs are exactly the
// A-fragment of mfma_16x16x16 for out = attn @ V.
__global__ __launch_bounds__(256) void attn_kernel(const bf16* __restrict__ qkv,
                                                   bf16* __restrict__ out) {
  const int t = threadIdx.x, w = t >> 6, lane = t & 63;
  const long tok = (long)blockIdx.x * 4 + w;
  const bf16* base = qkv + tok * 3072;  // [16 heads][q(64)|k(64)|v(64)]
  const int r = lane & 15, g4 = lane >> 4;

  const short8 ka0 = *(const short8*)(base + r * 192 + 64 + g4 * 8);
  const short8 ka1 = *(const short8*)(base + r * 192 + 96 + g4 * 8);
  const short8 qb0 = *(const short8*)(base + r * 192 + g4 * 8);
  const short8 qb1 = *(const short8*)(base + r * 192 + 32 + g4 * 8);
  f32x4 c = {0.f, 0.f, 0.f, 0.f};
  c = __builtin_amdgcn_mfma_f32_16x16x32_bf16(ka0, qb0, c, 0, 0, 0);
  c = __builtin_amdgcn_mfma_f32_16x16x32_bf16(ka1, qb1, c, 0, 0, 0);

  // scale + softmax over g (rows of scoresT)
  float s0 = c[0] * 0.125f, s1 = c[1] * 0.125f, s2 = c[2] * 0.125f, s3 = c[3] * 0.125f;
  float mx = fmaxf(fmaxf(s0, s1), fmaxf(s2, s3));
  mx = fmaxf(mx, __shfl_xor(mx, 16, 64));
  mx = fmaxf(mx, __shfl_xor(mx, 32, 64));
  const float e0 = __expf(s0 - mx), e1 = __expf(s1 - mx);
  const float e2 = __expf(s2 - mx), e3 = __expf(s3 - mx);
  float sum = e0 + e1 + e2 + e3;
  sum += __shfl_xor(sum, 16, 64);
  sum += __shfl_xor(sum, 32, 64);
  const float inv = 1.0f / sum;

#if __has_builtin(__builtin_amdgcn_mfma_f32_16x16x16bf16_1k)
  union { bf16 h[4]; short4v v; } pa;
  pa.h[0] = __float2bfloat16(e0 * inv);
  pa.h[1] = __float2bfloat16(e1 * inv);
  pa.h[2] = __float2bfloat16(e2 * inv);
  pa.h[3] = __float2bfloat16(e3 * inv);
#pragma unroll
  for (int ch = 0; ch < 4; ++ch) {
    union { bf16 h[4]; short4v v; } vb;
#pragma unroll
    for (int j = 0; j < 4; j++)
      vb.h[j] = base[(g4 * 4 + j) * 192 + 128 + ch * 16 + r];
    f32x4 o = {0.f, 0.f, 0.f, 0.f};
    o = __builtin_amdgcn_mfma_f32_16x16x16bf16_1k(pa.v, vb.v, o, 0, 0, 0);
#pragma unroll
    for (int i = 0; i < 4; i++)
      out[tok * 1024 + (g4 * 4 + i) * 64 + ch * 16 + r] = __float2bfloat16(o[i]);
  }
#else
  // fallback: LDS broadcast + VALU PV (correct, slower)
  __shared__ float sm[4][16][16];
#pragma unroll
  for (int i = 0; i < 4; i++) sm[w][g4 * 4 + i][r] = ((i == 0) ? e0 : (i == 1) ? e1 : (i == 2) ? e2 : e3) * inv;
  __syncthreads();
  const int d = lane;
  float o[16];
#pragma unroll
  for (int h = 0; h < 16; h++) o[h] = 0.f;
  for (int g = 0; g < 16; g++) {
    const float vg = __bfloat162float(base[g * 192 + 128 + d]);
#pragma unroll
    for (int h = 0; h < 16; h++) o[h] += sm[w][g][h] * vg;
  }
#pragma unroll
  for (int h = 0; h < 16; h++) out[tok * 1024 + h * 64 + d] = __float2bfloat16(o[h]);
#endif
}

extern "C" void kernel_launch(void* const* d_in, const int* in_sizes, int n_in,
                              void* d_out, int out_size, void* d_ws, size_t ws_size,
                              hipStream_t stream) {
  const float* x     = (const float*)d_in[0];
  const float* w_qkv = (const float*)d_in[1];
  const float* b_qkv = (const float*)d_in[2];
  const float* w_out = (const float*)d_in[3];
  const float* b_out = (const float*)d_in[4];
  float* outp = (float*)d_out;

  char* ws = (char*)d_ws;
  bf16* x_b   = (bf16*)(ws);                  // 65536*1024*2   = 128 MB
  bf16* wq_b  = (bf16*)(ws + 134217728L);     // 3072*1024*2    = 6 MB
  bf16* wo_b  = (bf16*)(ws + 140509184L);     // 1024*1024*2    = 2 MB
  bf16* qkv_b = (bf16*)(ws + 142606336L);     // 65536*3072*2   = 384 MB
  bf16* att_b = (bf16*)(ws + 545259520L);     // 65536*1024*2   = 128 MB

  cvt_kernel<<<2048, 256, 0, stream>>>(x, x_b, (long)N_TOK * C_DIM / 4);
  cvt_kernel<<<768, 256, 0, stream>>>(w_qkv, wq_b, (long)3 * C_DIM * C_DIM / 4);
  cvt_kernel<<<256, 256, 0, stream>>>(w_out, wo_b, (long)C_DIM * C_DIM / 4);

  gemm_bt<true><<<512 * 24, 256, 0, stream>>>(x_b, wq_b, b_qkv, qkv_b,
                                              N_TOK, 3 * C_DIM, C_DIM, 24);
  attn_kernel<<<N_TOK / 4, 256, 0, stream>>>(qkv_b, att_b);
  gemm_bt<false><<<512 * 8, 256, 0, stream>>>(att_b, wo_b, b_out, outp,
                                              N_TOK, C_DIM, C_DIM, 8);
}

// Round 2
// 1148.428 us; speedup vs baseline: 1.0896x; 1.0896x over previous
//
#include <hip/hip_runtime.h>
#include <hip/hip_bf16.h>

#define N_TOK 65536
#define C_DIM 1024

typedef __hip_bfloat16 bf16;
typedef short short8 __attribute__((ext_vector_type(8)));
typedef short short4v __attribute__((ext_vector_type(4)));
typedef float f32x4 __attribute__((ext_vector_type(4)));

__device__ __forceinline__ void gload_lds16(const bf16* g, bf16* l) {
  __builtin_amdgcn_global_load_lds(
      (const __attribute__((address_space(1))) void*)g,
      (__attribute__((address_space(3))) void*)l, 16, 0, 0);
}

__device__ __forceinline__ void barrier_raw() {
  asm volatile("" ::: "memory");
  __builtin_amdgcn_s_barrier();
  asm volatile("" ::: "memory");
}

#define VMCNT(n) asm volatile("s_waitcnt vmcnt(" #n ")" ::: "memory")

// ---------------- fp32 -> bf16 convert (vectorized) ----------------
__global__ void cvt_kernel(const float* __restrict__ in, bf16* __restrict__ out, long n4) {
  long i = (long)blockIdx.x * blockDim.x + threadIdx.x;
  const long stride = (long)gridDim.x * blockDim.x;
  for (; i < n4; i += stride) {
    const float4 v = ((const float4*)in)[i];
    union { bf16 h[4]; uint2 u; } p;
    p.h[0] = __float2bfloat16(v.x);
    p.h[1] = __float2bfloat16(v.y);
    p.h[2] = __float2bfloat16(v.z);
    p.h[3] = __float2bfloat16(v.w);
    ((uint2*)out)[i] = p.u;
  }
}

// ---------------- 256x256-tile bf16 GEMM, deep-pipelined ----------------
// C[m][n] = sum_k A[m][k]*B[n][k] + bias[n].  8 waves (2Mx4N), BK=64,
// dbuf=2 (128 KiB LDS), 4 phases/K-tile, half-tile staging, counted vmcnt,
// XOR-swizzled LDS (byte ^= (row&7)<<4), raw s_barrier, setprio MFMA clusters.
//
// Schedule per K-tile tt (buffers d=tt&1):
//  p0: vmcnt(4); bar; read a[m0-3],b[n0-1]; stage A(tt+1,h0); mfma m0-3 x n0-1
//  p1: bar; read b[n2-3];                  stage A(tt+1,h1); mfma m0-3 x n2-3
//  p2: bar; read a[m4-7];                  stage B(tt+2,h0); mfma m4-7 x n0-1
//  p3: bar;                                stage B(tt+2,h1); mfma m4-7 x n2-3
// Safety: stage A(tt+1,h) targets buffer of A(tt-1), last read at (tt-1,p2),
// barriers intervene. stage B(tt+2,h) targets B(tt), last read at (tt,p1),
// issued after bar(p2). vmcnt(4): after A(tt)h1 only B(tt+1) (4 loads) issued.
template<bool OUT_BF16>
__global__ __launch_bounds__(512, 2) void gemm256(
    const bf16* __restrict__ A, const bf16* __restrict__ B,
    const float* __restrict__ bias, void* __restrict__ Cv,
    int M, int N, int K, int ntm) {
  __shared__ __attribute__((aligned(16))) bf16 As[2][2][128 * 64];
  __shared__ __attribute__((aligned(16))) bf16 Bs[2][2][128 * 64];

  const int t = threadIdx.x;
  const int lane = t & 63, wid = t >> 6;
  const int wr = wid >> 2, wc = wid & 3;   // wave grid 2 x 4
  const int lr = lane & 15, g = lane >> 4;

  // XCD-aware bijective swizzle (grids are multiples of 8)
  const int nwg = gridDim.x;
  const int bid = blockIdx.x;
  const int swz = (bid & 7) * (nwg >> 3) + (bid >> 3);
  const int mt = swz % ntm;
  const int nt = swz / ntm;
  const long m0 = (long)mt * 256, n0 = (long)nt * 256;

  const bf16* Abase = A + m0 * K;
  const bf16* Bbase = B + n0 * K;

  // staging constants: thread t covers LDS linear bytes t*16 (+8KiB chunk).
  // row = t>>3 (+64), colbyte = (t&7)*16; source col pre-swizzled by (row&7)<<4.
  const int srow = t >> 3;
  const int scol = (((t & 7) << 4) ^ ((srow & 7) << 4)) >> 1;  // elems
  const int ldst = t * 8;                                      // elems

  // fragment-read constants: byte col = (ks*64 + g*16) ^ ((row&7)<<4), row&7==lr&7
  const int axor = (lr & 7) << 4;
  const int colk0 = ((0 + g * 16) ^ axor) >> 1;
  const int colk1 = ((64 + g * 16) ^ axor) >> 1;
  const int brow0 = (wc & 1) * 64;

  auto stageA = [&](int tt, int h) {
    bf16* dst = &As[tt & 1][h][0];
    const bf16* src = Abase + (long)(h * 128 + srow) * K + (long)tt * 64 + scol;
    gload_lds16(src, dst + ldst);
    gload_lds16(src + 64L * K, dst + 4096 + ldst);
  };
  auto stageB = [&](int tt, int h) {
    bf16* dst = &Bs[tt & 1][h][0];
    const bf16* src = Bbase + (long)(h * 128 + srow) * K + (long)tt * 64 + scol;
    gload_lds16(src, dst + 4096 * 0 + ldst);
    gload_lds16(src + 64L * K, dst + 4096 + ldst);
  };

  f32x4 acc[8][4];
#pragma unroll
  for (int m = 0; m < 8; ++m)
#pragma unroll
    for (int n = 0; n < 4; ++n) acc[m][n] = f32x4{0.f, 0.f, 0.f, 0.f};

  const int KT = K >> 6;
  // prologue: issue order must match steady state: B(0), A(0), B(1)
  stageB(0, 0); stageB(0, 1);
  stageA(0, 0); stageA(0, 1);
  stageB(1, 0); stageB(1, 1);

  short8 af[4][2], bq[4][2];

  for (int tt = 0; tt < KT; ++tt) {
    const int d = tt & 1;
    const bf16* Ah = &As[d][wr][0];
    const bf16* Bh = &Bs[d][wc >> 1][0];

    // ---------- phase 0 ----------
    if (tt < KT - 1) { VMCNT(4); } else { VMCNT(0); }
    barrier_raw();
#pragma unroll
    for (int m = 0; m < 4; ++m) {
      af[m][0] = *(const short8*)&Ah[(m * 16 + lr) * 64 + colk0];
      af[m][1] = *(const short8*)&Ah[(m * 16 + lr) * 64 + colk1];
    }
#pragma unroll
    for (int n = 0; n < 2; ++n) {
      bq[n][0] = *(const short8*)&Bh[(brow0 + n * 16 + lr) * 64 + colk0];
      bq[n][1] = *(const short8*)&Bh[(brow0 + n * 16 + lr) * 64 + colk1];
    }
    if (tt + 1 < KT) stageA(tt + 1, 0);
    __builtin_amdgcn_s_setprio(1);
#pragma unroll
    for (int m = 0; m < 4; ++m)
#pragma unroll
      for (int n = 0; n < 2; ++n) {
        acc[m][n] = __builtin_amdgcn_mfma_f32_16x16x32_bf16(af[m][0], bq[n][0], acc[m][n], 0, 0, 0);
        acc[m][n] = __builtin_amdgcn_mfma_f32_16x16x32_bf16(af[m][1], bq[n][1], acc[m][n], 0, 0, 0);
      }
    __builtin_amdgcn_s_setprio(0);

    // ---------- phase 1 ----------
    barrier_raw();
#pragma unroll
    for (int n = 2; n < 4; ++n) {
      bq[n][0] = *(const short8*)&Bh[(brow0 + n * 16 + lr) * 64 + colk0];
      bq[n][1] = *(const short8*)&Bh[(brow0 + n * 16 + lr) * 64 + colk1];
    }
    if (tt + 1 < KT) stageA(tt + 1, 1);
    __builtin_amdgcn_s_setprio(1);
#pragma unroll
    for (int m = 0; m < 4; ++m)
#pragma unroll
      for (int n = 2; n < 4; ++n) {
        acc[m][n] = __builtin_amdgcn_mfma_f32_16x16x32_bf16(af[m][0], bq[n][0], acc[m][n], 0, 0, 0);
        acc[m][n] = __builtin_amdgcn_mfma_f32_16x16x32_bf16(af[m][1], bq[n][1], acc[m][n], 0, 0, 0);
      }
    __builtin_amdgcn_s_setprio(0);

    // ---------- phase 2 ----------
    barrier_raw();
#pragma unroll
    for (int m = 0; m < 4; ++m) {
      af[m][0] = *(const short8*)&Ah[((m + 4) * 16 + lr) * 64 + colk0];
      af[m][1] = *(const short8*)&Ah[((m + 4) * 16 + lr) * 64 + colk1];
    }
    if (tt + 2 < KT) stageB(tt + 2, 0);
    __builtin_amdgcn_s_setprio(1);
#pragma unroll
    for (int m = 0; m < 4; ++m)
#pragma unroll
      for (int n = 0; n < 2; ++n) {
        acc[m + 4][n] = __builtin_amdgcn_mfma_f32_16x16x32_bf16(af[m][0], bq[n][0], acc[m + 4][n], 0, 0, 0);
        acc[m + 4][n] = __builtin_amdgcn_mfma_f32_16x16x32_bf16(af[m][1], bq[n][1], acc[m + 4][n], 0, 0, 0);
      }
    __builtin_amdgcn_s_setprio(0);

    // ---------- phase 3 ----------
    barrier_raw();
    if (tt + 2 < KT) stageB(tt + 2, 1);
    __builtin_amdgcn_s_setprio(1);
#pragma unroll
    for (int m = 0; m < 4; ++m)
#pragma unroll
      for (int n = 2; n < 4; ++n) {
        acc[m + 4][n] = __builtin_amdgcn_mfma_f32_16x16x32_bf16(af[m][0], bq[n][0], acc[m + 4][n], 0, 0, 0);
        acc[m + 4][n] = __builtin_amdgcn_mfma_f32_16x16x32_bf16(af[m][1], bq[n][1], acc[m + 4][n], 0, 0, 0);
      }
    __builtin_amdgcn_s_setprio(0);
  }

  // epilogue: C row = m0 + wr*128 + m*16 + g*4 + q, col = n0 + wc*64 + n*16 + lr
  const long orow0 = m0 + wr * 128;
  const long ocol0 = n0 + wc * 64;
  float bv[4];
#pragma unroll
  for (int n = 0; n < 4; ++n) bv[n] = bias[ocol0 + n * 16 + lr];
#pragma unroll
  for (int m = 0; m < 8; ++m) {
#pragma unroll
    for (int q = 0; q < 4; ++q) {
      const long row = orow0 + m * 16 + g * 4 + q;
#pragma unroll
      for (int n = 0; n < 4; ++n) {
        const float v = acc[m][n][q] + bv[n];
        const long col = ocol0 + n * 16 + lr;
        if constexpr (OUT_BF16)
          ((bf16*)Cv)[row * N + col] = __float2bfloat16(v);
        else
          ((float*)Cv)[row * N + col] = v;
      }
    }
  }
}

// ---------------- per-token 16x16 attention, 1 wave/token ----------------
__global__ __launch_bounds__(256) void attn_kernel(const bf16* __restrict__ qkv,
                                                   bf16* __restrict__ out) {
  const int t = threadIdx.x, w = t >> 6, lane = t & 63;
  const long tok = (long)blockIdx.x * 4 + w;
  const bf16* base = qkv + tok * 3072;  // [16 heads][q(64)|k(64)|v(64)]
  const int r = lane & 15, g4 = lane >> 4;

  const short8 ka0 = *(const short8*)(base + r * 192 + 64 + g4 * 8);
  const short8 ka1 = *(const short8*)(base + r * 192 + 96 + g4 * 8);
  const short8 qb0 = *(const short8*)(base + r * 192 + g4 * 8);
  const short8 qb1 = *(const short8*)(base + r * 192 + 32 + g4 * 8);
  f32x4 c = {0.f, 0.f, 0.f, 0.f};
  c = __builtin_amdgcn_mfma_f32_16x16x32_bf16(ka0, qb0, c, 0, 0, 0);
  c = __builtin_amdgcn_mfma_f32_16x16x32_bf16(ka1, qb1, c, 0, 0, 0);

  float s0 = c[0] * 0.125f, s1 = c[1] * 0.125f, s2 = c[2] * 0.125f, s3 = c[3] * 0.125f;
  float mx = fmaxf(fmaxf(s0, s1), fmaxf(s2, s3));
  mx = fmaxf(mx, __shfl_xor(mx, 16, 64));
  mx = fmaxf(mx, __shfl_xor(mx, 32, 64));
  const float e0 = __expf(s0 - mx), e1 = __expf(s1 - mx);
  const float e2 = __expf(s2 - mx), e3 = __expf(s3 - mx);
  float sum = e0 + e1 + e2 + e3;
  sum += __shfl_xor(sum, 16, 64);
  sum += __shfl_xor(sum, 32, 64);
  const float inv = 1.0f / sum;

  union { bf16 h[4]; short4v v; } pa;
  pa.h[0] = __float2bfloat16(e0 * inv);
  pa.h[1] = __float2bfloat16(e1 * inv);
  pa.h[2] = __float2bfloat16(e2 * inv);
  pa.h[3] = __float2bfloat16(e3 * inv);
#pragma unroll
  for (int ch = 0; ch < 4; ++ch) {
    union { bf16 h[4]; short4v v; } vb;
#pragma unroll
    for (int j = 0; j < 4; j++)
      vb.h[j] = base[(g4 * 4 + j) * 192 + 128 + ch * 16 + r];
    f32x4 o = {0.f, 0.f, 0.f, 0.f};
    o = __builtin_amdgcn_mfma_f32_16x16x16bf16_1k(pa.v, vb.v, o, 0, 0, 0);
#pragma unroll
    for (int i = 0; i < 4; i++)
      out[tok * 1024 + (g4 * 4 + i) * 64 + ch * 16 + r] = __float2bfloat16(o[i]);
  }
}

extern "C" void kernel_launch(void* const* d_in, const int* in_sizes, int n_in,
                              void* d_out, int out_size, void* d_ws, size_t ws_size,
                              hipStream_t stream) {
  const float* x     = (const float*)d_in[0];
  const float* w_qkv = (const float*)d_in[1];
  const float* b_qkv = (const float*)d_in[2];
  const float* w_out = (const float*)d_in[3];
  const float* b_out = (const float*)d_in[4];
  float* outp = (float*)d_out;

  char* ws = (char*)d_ws;
  bf16* x_b   = (bf16*)(ws);                  // 65536*1024*2   = 128 MB
  bf16* wq_b  = (bf16*)(ws + 134217728L);     // 3072*1024*2    = 6 MB
  bf16* wo_b  = (bf16*)(ws + 140509184L);     // 1024*1024*2    = 2 MB
  bf16* qkv_b = (bf16*)(ws + 142606336L);     // 65536*3072*2   = 384 MB
  bf16* att_b = (bf16*)(ws + 545259520L);     // 65536*1024*2   = 128 MB

  cvt_kernel<<<2048, 256, 0, stream>>>(x, x_b, (long)N_TOK * C_DIM / 4);
  cvt_kernel<<<768, 256, 0, stream>>>(w_qkv, wq_b, (long)3 * C_DIM * C_DIM / 4);
  cvt_kernel<<<256, 256, 0, stream>>>(w_out, wo_b, (long)C_DIM * C_DIM / 4);

  gemm256<true><<<(N_TOK / 256) * (3 * C_DIM / 256), 512, 0, stream>>>(
      x_b, wq_b, b_qkv, qkv_b, N_TOK, 3 * C_DIM, C_DIM, N_TOK / 256);
  attn_kernel<<<N_TOK / 4, 256, 0, stream>>>(qkv_b, att_b);
  gemm256<false><<<(N_TOK / 256) * (C_DIM / 256), 512, 0, stream>>>(
      att_b, wo_b, b_out, outp, N_TOK, C_DIM, C_DIM, N_TOK / 256);
}